// Round 12
// baseline (57.375 us; speedup 1.0000x reference)
//
#include <hip/hip_runtime.h>
#include <stdint.h>

// LocalAggregation (PointNet++ SA layer, B=4 N=4096 C=32 K=32, 35->64->64)
//
// 5-kernel pipeline (all-256-thr front, bf16 u AND q):
//  K1 front  : blocks [0,512): uq, 32 pts/block (8 thr/pt): u=W1[:,3:]x+W1[:,:3]p [bf16],
//              q=W1[:,:3]p [bf16 packed]; blocks 512..515: per-batch grid build
//              (cell=0.1, 10^3 cells, wave-shuffle scan, 2 barriers); block 516: prep.
//  K2 query  : grid ball query, 1 wave/query, 4 independent waves/block, no barriers.
//              9 merged column segments, converged shuffles, 4096-bit LDS bitmap ->
//              ascending-j extraction (== "first 32 ascending, pad first").
//  K3 bn1    : coalesced bf16 gather (idx/q staged in LDS, 4 lanes/row) -> per-channel
//              sum/sumsq -> shuffle+LDS reduce -> atomicAdd part1b[xcd][128]
//  K4 stage2 : inline BN1 finalize; coalesced bf16 row-gather -> h -> swizzled LDS
//              tile -> MFMA conv2; per-(n,o) max/min over k; BN2 partials
//  K5 out    : inline BN2 finalize; 64x64 LDS transpose, coalesced.

#define R2 0.01f
#define INVM (1.0f / 524288.0f)

typedef __bf16 bf16x8 __attribute__((ext_vector_type(8)));
typedef float f32x4 __attribute__((ext_vector_type(4)));

__device__ __forceinline__ uint32_t pack_bf16(float a, float b) {
  uint32_t ua = __float_as_uint(a), ub = __float_as_uint(b);
  ua += 0x7fffu + ((ua >> 16) & 1u);
  ub += 0x7fffu + ((ub >> 16) & 1u);
  return (ua >> 16) | (ub & 0xffff0000u);
}
__device__ __forceinline__ float bf_lo(uint32_t v) { return __uint_as_float(v << 16); }
__device__ __forceinline__ float bf_hi(uint32_t v) { return __uint_as_float(v & 0xffff0000u); }

__device__ __forceinline__ int cell_of(float v) {
  const int c = (int)(v * 10.f);
  return c > 9 ? 9 : c;
}

// ---------------- K1: uq + grid build + prep (all 256-thr blocks) ----------------
__global__ __launch_bounds__(256) void k_front(const float* __restrict__ p,
                                               const float* __restrict__ x,
                                               const float* __restrict__ W1,
                                               const float* __restrict__ W2,
                                               void* __restrict__ u,
                                               void* __restrict__ qpk,
                                               uint32_t* __restrict__ w2frag,
                                               float* __restrict__ part1b,
                                               float* __restrict__ part2b,
                                               float4* __restrict__ cellpts,
                                               int* __restrict__ cellStart) {
  __shared__ __align__(16) char smraw[8960];
  const int bid = blockIdx.x, tid = threadIdx.x;

  if (bid < 512) {
    // ---- uq: 32 points/block, 8 threads/point ----
    float* W1s = (float*)smraw;   // transposed [c][64]
    for (int tt = tid; tt < 2240; tt += 256) {
      const int o = tt / 35, cc = tt - o * 35;
      W1s[(cc << 6) + o] = W1[tt];
    }
    __syncthreads();
    const int g = (bid << 5) + (tid & 31);   // global point id
    const int b = g >> 12, nl = g & 4095;
    const int os = (tid >> 5) << 3;          // 8-output slice
    float f[35];
    const float* pb = p + g * 3;
    f[0] = pb[0]; f[1] = pb[1]; f[2] = pb[2];
    const float* xb = x + (b << 17) + nl;
#pragma unroll
    for (int cc = 0; cc < 32; ++cc) f[3 + cc] = xb[cc << 12];
    float acc[8];
#pragma unroll
    for (int o = 0; o < 8; ++o) acc[o] = 0.f;
#pragma unroll
    for (int cc = 0; cc < 35; ++cc) {
      const float fc = f[cc];
      const float4* wp = (const float4*)(W1s + (cc << 6) + os);
      const float4 w0 = wp[0], w1 = wp[1];
      acc[0] = fmaf(w0.x, fc, acc[0]); acc[1] = fmaf(w0.y, fc, acc[1]);
      acc[2] = fmaf(w0.z, fc, acc[2]); acc[3] = fmaf(w0.w, fc, acc[3]);
      acc[4] = fmaf(w1.x, fc, acc[4]); acc[5] = fmaf(w1.y, fc, acc[5]);
      acc[6] = fmaf(w1.z, fc, acc[6]); acc[7] = fmaf(w1.w, fc, acc[7]);
      if (cc == 2) {
        uint4 qp4;
        qp4.x = pack_bf16(acc[0], acc[1]); qp4.y = pack_bf16(acc[2], acc[3]);
        qp4.z = pack_bf16(acc[4], acc[5]); qp4.w = pack_bf16(acc[6], acc[7]);
        *(uint4*)((char*)qpk + ((size_t)g << 7) + (os << 1)) = qp4;
      }
    }
    uint4 pk;
    pk.x = pack_bf16(acc[0], acc[1]); pk.y = pack_bf16(acc[2], acc[3]);
    pk.z = pack_bf16(acc[4], acc[5]); pk.w = pack_bf16(acc[6], acc[7]);
    *(uint4*)((char*)u + ((size_t)g << 7) + (os << 1)) = pk;
    return;
  }

  if (bid < 516) {
    // ---- grid build for batch (bid-512), 256 thr, wave-shuffle scan ----
    int* cnt_s = (int*)smraw;         // 1024 ints
    int* wsum = (int*)(smraw + 4096); // 4 wave totals
    const int b = bid - 512;
    const float* pb = p + b * 12288;
    for (int i = tid; i < 1024; i += 256) cnt_s[i] = 0;
    __syncthreads();
    for (int i = tid; i < 4096; i += 256) {
      const float xx = pb[3 * i], yy = pb[3 * i + 1], zz = pb[3 * i + 2];
      const int c = (cell_of(xx) * 10 + cell_of(yy)) * 10 + cell_of(zz);
      atomicAdd(&cnt_s[c], 1);
    }
    __syncthreads();
    // chunked scan: thread t owns cells [4t,4t+4)
    int c0 = 0, c1 = 0, c2 = 0, c3 = 0;
    if (tid < 250) {
      c0 = cnt_s[4 * tid]; c1 = cnt_s[4 * tid + 1];
      c2 = cnt_s[4 * tid + 2]; c3 = cnt_s[4 * tid + 3];
    }
    const int chunk = c0 + c1 + c2 + c3;
    int incl = chunk;
#pragma unroll
    for (int d = 1; d < 64; d <<= 1) { const int t = __shfl_up(incl, d); if ((tid & 63) >= d) incl += t; }
    const int w = tid >> 6, lane = tid & 63;
    if (lane == 63) wsum[w] = incl;
    __syncthreads();
    int wpre = 0;
    for (int i = 0; i < w; ++i) wpre += wsum[i];
    const int excl = wpre + incl - chunk;
    if (tid < 250) {
      int* cs = cellStart + b * 1001 + 4 * tid;
      cs[0] = excl;           cs[1] = excl + c0;
      cs[2] = excl + c0 + c1; cs[3] = excl + c0 + c1 + c2;
    }
    if (tid == 0) cellStart[b * 1001 + 1000] = 4096;
    __syncthreads();
    if (tid < 250) {
      cnt_s[4 * tid] = excl;           cnt_s[4 * tid + 1] = excl + c0;
      cnt_s[4 * tid + 2] = excl + c0 + c1; cnt_s[4 * tid + 3] = excl + c0 + c1 + c2;
    }
    __syncthreads();
    for (int i = tid; i < 4096; i += 256) {
      const float xx = pb[3 * i], yy = pb[3 * i + 1], zz = pb[3 * i + 2];
      const int c = (cell_of(xx) * 10 + cell_of(yy)) * 10 + cell_of(zz);
      const int pos = atomicAdd(&cnt_s[c], 1);
      cellpts[(b << 12) + pos] = make_float4(xx, yy, zz, __int_as_float(i));
    }
    return;
  }

  // ---- prep (block 516): w2frag pack + zero atomic accumulators ----
  for (int tt = tid; tt < 2048; tt += 256) {
    const int e2 = tt & 3, lane = (tt >> 2) & 63, frag = tt >> 8;
    const int kt = frag >> 2, ot = frag & 3;
    const int c0 = kt * 32 + ((lane >> 4) << 3) + e2 * 2;
    const int o = ot * 16 + (lane & 15);
    w2frag[tt] = pack_bf16(W2[(o << 6) + c0], W2[(o << 6) + c0 + 1]);
  }
  for (int i = tid; i < 1024; i += 256) { part1b[i] = 0.f; part2b[i] = 0.f; }
}

// ---------------- K2: grid ball query (4 independent waves, no barriers) ----------------
__global__ __launch_bounds__(256) void k_query(const float* __restrict__ p,
                                               const float4* __restrict__ cellpts,
                                               const int* __restrict__ cellStart,
                                               int* __restrict__ idx) {
  __shared__ uint32_t bm[4][128];     // per-wave 4096-bit bitmap
  const int tid = threadIdx.x, w = tid >> 6, lane = tid & 63;
  const int blk0 = blockIdx.x;                        // 4096 blocks
  const int blkS = ((blk0 & 7) << 9) + (blk0 >> 3);   // bijective XCD swizzle
  const int n = (blkS << 2) + w;                      // query id
  const int b = n >> 12;
  bm[w][lane] = 0; bm[w][64 + lane] = 0;
  const float qx = p[n * 3], qy = p[n * 3 + 1], qz = p[n * 3 + 2];  // wave-uniform
  const int cxq = cell_of(qx), cyq = cell_of(qy), czq = cell_of(qz);

  // 9 column segments in lanes 0..8 (z-cells [cz-1,cz+1] contiguous per column)
  int cnt_l = 0, startG = 0;
  if (lane < 9) {
    const int cx = cxq + lane / 3 - 1;
    const int cy = cyq + lane % 3 - 1;
    if ((unsigned)cx < 10u && (unsigned)cy < 10u) {
      const int zlo = czq > 0 ? czq - 1 : 0;
      const int zhi = czq < 9 ? czq + 1 : 9;
      const int* cs = cellStart + b * 1001 + (cx * 10 + cy) * 10;
      startG = cs[zlo];
      cnt_l = cs[zhi + 1] - startG;
    }
  }
  int incl = cnt_l;
#pragma unroll
  for (int d = 1; d < 64; d <<= 1) { const int t = __shfl_up(incl, d); if (lane >= d) incl += t; }
  const int T = __shfl(incl, 63);
  const int base_l = startG - (incl - cnt_l);

  for (int tb = 0; tb < T; tb += 64) {
    const int t = tb + lane;
    int s = 0;
#pragma unroll
    for (int m = 0; m < 9; ++m) s += (__shfl(incl, m) <= t);
    const int a = __shfl(base_l, s < 9 ? s : 8);
    if (t < T) {
      const float4 cp = cellpts[(b << 12) + a + t];
      const float dx = cp.x - qx, dy = cp.y - qy, dz = cp.z - qz;
      // match numpy fp32 (no fma contraction, same summation order)
      const float d2 = __fadd_rn(__fadd_rn(__fmul_rn(dx, dx), __fmul_rn(dy, dy)),
                                 __fmul_rn(dz, dz));
      if (d2 < R2) {
        const int j = __float_as_int(cp.w);
        atomicOr(&bm[w][j >> 5], 1u << (j & 31));
      }
    }
  }
  __threadfence_block();

  // ascending-j extraction == "first 32 ascending, pad with first"
  const uint2 wp2 = *(const uint2*)&bm[w][2 * lane];
  unsigned long long wd = ((unsigned long long)wp2.y << 32) | wp2.x;
  const int pc = __popcll(wd);
  int ip = pc;
#pragma unroll
  for (int d = 1; d < 64; d <<= 1) { const int t = __shfl_up(ip, d); if (lane >= d) ip += t; }
  const int cntT = __shfl(ip, 63);
  int bpos = ip - pc;
  const unsigned long long nz = __ballot(wd != 0ull);
  const int fl = (int)__builtin_ctzll(nz);
  const int fv = wd ? ((lane << 6) + (int)__builtin_ctzll(wd)) : 0;
  const int first = __shfl(fv, fl);
  int* row = idx + (n << 5);
  unsigned long long ww = wd;
  while (ww && bpos < 32) {
    const int j = (lane << 6) + (int)__builtin_ctzll(ww);
    row[bpos] = j;
    ++bpos;
    ww &= ww - 1;
  }
  for (int s = cntT + lane; s < 32; s += 64) row[s] = first;
}

// ---------------- K3: BN1 stats, coalesced bf16 gather (4 lanes/row) ----------------
__global__ __launch_bounds__(256) void k_bn1(const void* __restrict__ u,
                                             const void* __restrict__ qpk,
                                             const int* __restrict__ idx,
                                             float* __restrict__ part1b) {
  __shared__ int idxs[512];
  __shared__ __align__(16) float qs[1024];   // 16 pts x 64 ch (f32, unpacked)
  __shared__ float red[8][64];
  const int tid = threadIdx.x;
  const int blk0 = blockIdx.x;
  const int blkS = ((blk0 & 7) << 7) + (blk0 >> 3);   // bijective XCD swizzle
  const int p0 = blkS << 4;
  const int bb = (p0 >> 12) << 12;
  idxs[tid] = idx[(p0 << 5) + tid];
  idxs[256 + tid] = idx[(p0 << 5) + 256 + tid];
  const uint32_t* qp32 = (const uint32_t*)qpk;
#pragma unroll
  for (int i = 0; i < 2; ++i) {
    const int e = (i << 8) + tid;            // 512 pairs
    const uint32_t v = qp32[(p0 << 5) + e];
    qs[2 * e] = bf_lo(v); qs[2 * e + 1] = bf_hi(v);
  }
  __syncthreads();
  const int c4 = tid & 3;
  const char* ub = (const char*)u;
  float s1[16], s2[16];
#pragma unroll
  for (int i = 0; i < 16; ++i) { s1[i] = 0.f; s2[i] = 0.f; }
#pragma unroll 2
  for (int pass = 0; pass < 8; ++pass) {
    const int r = (pass << 6) + (tid >> 2);   // sample row 0..511
    const int j = idxs[r];
    const int pt = r >> 5;
    const uint4* up = (const uint4*)(ub + ((size_t)(bb + j) << 7) + (c4 << 5));
    const uint4 u0 = up[0], u1 = up[1];
    const float* qp = qs + (pt << 6) + (c4 << 4);
    const uint32_t uw[8] = {u0.x, u0.y, u0.z, u0.w, u1.x, u1.y, u1.z, u1.w};
#pragma unroll
    for (int e = 0; e < 8; ++e) {
      const float y0 = bf_lo(uw[e]) - qp[2 * e];
      const float y1 = bf_hi(uw[e]) - qp[2 * e + 1];
      s1[2 * e] += y0;     s2[2 * e] = fmaf(y0, y0, s2[2 * e]);
      s1[2 * e + 1] += y1; s2[2 * e + 1] = fmaf(y1, y1, s2[2 * e + 1]);
    }
  }
#pragma unroll
  for (int i = 0; i < 16; ++i) {
#pragma unroll
    for (int d = 4; d <= 32; d <<= 1) {
      s1[i] += __shfl_xor(s1[i], d);
      s2[i] += __shfl_xor(s2[i], d);
    }
  }
  const int w = tid >> 6, l = tid & 63;
  if (l < 4) {
#pragma unroll
    for (int i = 0; i < 16; ++i) {
      const int ch = (l << 4) + i;
      red[(w << 1)][ch] = s1[i];
      red[(w << 1) + 1][ch] = s2[i];
    }
  }
  __syncthreads();
  if (tid < 128) {
    const int ch = tid & 63, stat = tid >> 6;
    const float v = red[stat][ch] + red[2 + stat][ch] + red[4 + stat][ch] + red[6 + stat][ch];
    atomicAdd(&part1b[((blk0 & 7) << 7) + (stat << 6) + ch], v);   // XCD-private
  }
}

// ---------------- K4: coalesced bf16-gather MFMA conv2 + k-reduce + BN2 partials ----------------
__global__ __launch_bounds__(256) void k_stage2(const void* __restrict__ u,
                                                const int* __restrict__ idx,
                                                const void* __restrict__ qpk,
                                                const float* __restrict__ part1b,
                                                const float* __restrict__ g1,
                                                const float* __restrict__ b1,
                                                const uint32_t* __restrict__ w2frag,
                                                float* __restrict__ part2b,
                                                float* __restrict__ ymax,
                                                float* __restrict__ ymin) {
  __shared__ uint32_t hl[8192];   // 32 KB h tile: 256 samples x 128 B
  __shared__ float rs[8][64];     // rs = c1 - a1*q per (point, ch)
  __shared__ int   idxs[256];
  __shared__ float ac[128];
  __shared__ float red[8][64];
  const int tid = threadIdx.x, w = tid >> 6, l = tid & 63;
  const int blk0 = blockIdx.x;
  const int blk = ((blk0 & 7) << 8) + (blk0 >> 3);   // bijective XCD swizzle
  const int p0 = blk << 3;
  const int bb = (p0 >> 12) << 12;

  idxs[tid] = idx[(p0 << 5) + tid];
  const uint32_t qw = ((const uint32_t*)qpk)[(p0 << 5) + tid];  // 8 pts x 32 pairs
  if (tid < 64) {
    float s1 = 0.f, s2 = 0.f;
#pragma unroll
    for (int xx = 0; xx < 8; ++xx) {
      s1 += part1b[(xx << 7) + tid];
      s2 += part1b[(xx << 7) + 64 + tid];
    }
    const float mean = s1 * INVM, var = s2 * INVM - mean * mean;
    const float a = g1[tid] * rsqrtf(var + 1e-5f);
    ac[tid] = a; ac[64 + tid] = b1[tid] - mean * a;
  }
  __syncthreads();
  {
    const int pt = tid >> 5, pr = tid & 31;
    rs[pt][2 * pr]     = fmaf(-ac[2 * pr], bf_lo(qw), ac[64 + 2 * pr]);
    rs[pt][2 * pr + 1] = fmaf(-ac[2 * pr + 1], bf_hi(qw), ac[64 + 2 * pr + 1]);
  }
  __syncthreads();

  // ---- phase 1: bf16 row gather (4 lanes/row), h = relu(a1*u + rs), swizzled LDS
  const int c = tid & 3;
  const char* ub = (const char*)u;
  f32x4 av[4];
#pragma unroll
  for (int k = 0; k < 4; ++k) av[k] = *(const f32x4*)&ac[(c << 4) + (k << 2)];
#pragma unroll
  for (int pass = 0; pass < 4; ++pass) {
    const int r = (pass << 6) + (tid >> 2);
    const int pt = r >> 5;
    const int j = idxs[r];
    const uint4* up = (const uint4*)(ub + ((size_t)(bb + j) << 7) + (c << 5));
    const uint4 u0 = up[0], u1 = up[1];
    f32x4 rv4[4];
#pragma unroll
    for (int k = 0; k < 4; ++k) rv4[k] = *(const f32x4*)&rs[pt][(c << 4) + (k << 2)];
    const uint32_t uw8[8] = {u0.x, u0.y, u0.z, u0.w, u1.x, u1.y, u1.z, u1.w};
    uint32_t pk[8];
#pragma unroll
    for (int e = 0; e < 8; ++e) {
      const int i0 = 2 * e, i1 = 2 * e + 1;
      const float h0 = fmaxf(fmaf(av[i0 >> 2][i0 & 3], bf_lo(uw8[e]), rv4[i0 >> 2][i0 & 3]), 0.f);
      const float h1 = fmaxf(fmaf(av[i1 >> 2][i1 & 3], bf_hi(uw8[e]), rv4[i1 >> 2][i1 & 3]), 0.f);
      pk[e] = pack_bf16(h0, h1);
    }
    const int byte0 = (r << 7) + (c << 5);
    const int sw = (r & 7) << 4;
    *(uint4*)((char*)hl + (byte0 ^ sw)) = make_uint4(pk[0], pk[1], pk[2], pk[3]);
    *(uint4*)((char*)hl + ((byte0 + 16) ^ sw)) = make_uint4(pk[4], pk[5], pk[6], pk[7]);
  }

  bf16x8 bfr[8];
#pragma unroll
  for (int f = 0; f < 8; ++f)
    bfr[f] = __builtin_bit_cast(bf16x8, *(const uint4*)&w2frag[(f << 8) + (l << 2)]);
  __syncthreads();

  // ---- phase 2: per point: 16 MFMAs, stats
  float sm_[4] = {0.f, 0.f, 0.f, 0.f}, sq[4] = {0.f, 0.f, 0.f, 0.f};
#pragma unroll 1
  for (int pi = 0; pi < 2; ++pi) {
    const int ptl = (w << 1) + pi;
    const int pn = p0 + ptl;
    float mx[4], mn[4];
#pragma unroll
    for (int ot = 0; ot < 4; ++ot) { mx[ot] = -3e38f; mn[ot] = 3e38f; }
#pragma unroll
    for (int kt2 = 0; kt2 < 2; ++kt2) {
      bf16x8 afr[2];
#pragma unroll
      for (int kt = 0; kt < 2; ++kt) {
        const int srow = (ptl << 5) + (kt2 << 4) + (l & 15);
        int byte = (srow << 7) + (kt << 6) + ((l >> 4) << 4);
        byte ^= (srow & 7) << 4;
        afr[kt] = *(const bf16x8*)((const char*)hl + byte);
      }
#pragma unroll
      for (int ot = 0; ot < 4; ++ot) {
        f32x4 acc = {0.f, 0.f, 0.f, 0.f};
        acc = __builtin_amdgcn_mfma_f32_16x16x32_bf16(afr[0], bfr[ot], acc, 0, 0, 0);
        acc = __builtin_amdgcn_mfma_f32_16x16x32_bf16(afr[1], bfr[4 + ot], acc, 0, 0, 0);
#pragma unroll
        for (int e = 0; e < 4; ++e) {
          const float v = acc[e];
          mx[ot] = fmaxf(mx[ot], v); mn[ot] = fminf(mn[ot], v);
          sm_[ot] += v; sq[ot] = fmaf(v, v, sq[ot]);
        }
      }
    }
#pragma unroll
    for (int ot = 0; ot < 4; ++ot) {
      float a = fmaxf(mx[ot], __shfl_xor(mx[ot], 16)); a = fmaxf(a, __shfl_xor(a, 32));
      float b = fminf(mn[ot], __shfl_xor(mn[ot], 16)); b = fminf(b, __shfl_xor(b, 32));
      const int o = (ot << 4) + (l & 15);
      if (l < 16)      ymax[(pn << 6) + o] = a;
      else if (l < 32) ymin[(pn << 6) + o] = b;
    }
  }
#pragma unroll
  for (int ot = 0; ot < 4; ++ot) {
    float s = sm_[ot]; s += __shfl_xor(s, 16); s += __shfl_xor(s, 32);
    float t2 = sq[ot]; t2 += __shfl_xor(t2, 16); t2 += __shfl_xor(t2, 32);
    if (l < 16) { red[w][(ot << 4) + l] = s; red[4 + w][(ot << 4) + l] = t2; }
  }
  __syncthreads();
  if (tid < 128) {
    const int ch = tid & 63, sel = (tid >= 64) ? 4 : 0;
    const float v = red[sel][ch] + red[sel + 1][ch] + red[sel + 2][ch] + red[sel + 3][ch];
    atomicAdd(&part2b[((blk0 & 7) << 7) + tid], v);
  }
}

// ---------------- K5: output (inline a2c2 + LDS 64x64 transpose) ----------------
__global__ __launch_bounds__(256) void k_out(const float* __restrict__ ymax,
                                             const float* __restrict__ ymin,
                                             const float* __restrict__ part2b,
                                             const float* __restrict__ g2,
                                             const float* __restrict__ b2,
                                             float* __restrict__ out) {
  __shared__ float ac[128];
  __shared__ float tile[64][65];
  const int tid = threadIdx.x;
  if (tid < 64) {
    float s1 = 0.f, s2 = 0.f;
#pragma unroll
    for (int xx = 0; xx < 8; ++xx) {
      s1 += part2b[(xx << 7) + tid];
      s2 += part2b[(xx << 7) + 64 + tid];
    }
    const float mean = s1 * INVM, var = s2 * INVM - mean * mean;
    const float a = g2[tid] * rsqrtf(var + 1e-5f);
    ac[tid] = a; ac[64 + tid] = b2[tid] - mean * a;
  }
  __syncthreads();
  const int b = blockIdx.x >> 6, nt = blockIdx.x & 63;
  const int pnbase = (b << 12) + (nt << 6);
#pragma unroll
  for (int i = 0; i < 16; ++i) {
    const int e = i * 256 + tid;
    const int nl = e >> 6, o = e & 63;
    const float a = ac[o], c = ac[64 + o];
    const int src = ((pnbase + nl) << 6) + o;
    const float v = (a >= 0.f) ? ymax[src] : ymin[src];
    tile[nl][o] = fmaxf(fmaf(a, v, c), 0.f);
  }
  __syncthreads();
#pragma unroll
  for (int i = 0; i < 16; ++i) {
    const int e = i * 256 + tid;
    const int ol = e >> 6, nl = e & 63;
    out[(b << 18) + (ol << 12) + (nt << 6) + nl] = tile[nl][ol];
  }
}

extern "C" void kernel_launch(void* const* d_in, const int* in_sizes, int n_in,
                              void* d_out, int out_size, void* d_ws, size_t ws_size,
                              hipStream_t stream) {
  const float* p  = (const float*)d_in[0];
  const float* x  = (const float*)d_in[1];
  const float* W1 = (const float*)d_in[2];
  const float* g1 = (const float*)d_in[3];
  const float* b1 = (const float*)d_in[4];
  const float* W2 = (const float*)d_in[5];
  const float* g2 = (const float*)d_in[6];
  const float* b2 = (const float*)d_in[7];
  float* out = (float*)d_out;

  char* ws = (char*)d_ws;
  size_t off = 0;
  int* idx        = (int*)(ws + off);      off += 2097152;   // B*N*32 int
  void* u         = (void*)(ws + off);     off += 2097152;   // B*N*64 bf16
  void* qpk       = (void*)(ws + off);     off += 2097152;   // B*N*64 bf16 packed
  uint32_t* w2f   = (uint32_t*)(ws + off); off += 8192;
  float* part1b   = (float*)(ws + off);    off += 4096;      // [8][128] XCD-private
  float* part2b   = (float*)(ws + off);    off += 4096;
  float* ymax     = (float*)(ws + off);    off += 4194304;
  float* ymin     = (float*)(ws + off);    off += 4194304;
  float4* cellpts = (float4*)(ws + off);   off += 262144;    // [B][4096] float4
  int* cellStart  = (int*)(ws + off);      off += 16384;     // [B][1001]

  k_front<<<dim3(517), dim3(256), 0, stream>>>(p, x, W1, W2, u, qpk, w2f,
                                               part1b, part2b, cellpts, cellStart);
  k_query<<<dim3(4096), dim3(256), 0, stream>>>(p, cellpts, cellStart, idx);
  k_bn1<<<dim3(1024), dim3(256), 0, stream>>>(u, qpk, idx, part1b);
  k_stage2<<<dim3(2048), dim3(256), 0, stream>>>(u, idx, qpk, part1b, g1, b1, w2f,
                                                 part2b, ymax, ymin);
  k_out<<<dim3(256), dim3(256), 0, stream>>>(ymax, ymin, part2b, g2, b2, out);
}

// Round 13
// 54.658 us; speedup vs baseline: 1.0497x; 1.0497x over previous
//
#include <hip/hip_runtime.h>
#include <stdint.h>

// LocalAggregation (PointNet++ SA layer, B=4 N=4096 C=32 K=32, 35->64->64)
//
// 5-kernel pipeline (r11 structure + packed bf16 ymax/ymin):
//  K1 front  : blocks [0,128): uq (u = W1[:,3:]x + W1[:,:3]p [bf16]; q = W1[:,:3]p [f32])
//              block 128: W2 MFMA-frag pack, zero part1b/part2b
//              blocks [129,133): per-batch uniform grid build (cell=0.1, 10^3 cells)
//  K2 query  : grid ball query, 1 wave/query, 4 independent waves/block, no barriers.
//              9 merged column segments, converged shuffles, 4096-bit LDS bitmap ->
//              ascending-j extraction (== "first 32 ascending, pad first")
//  K3 bn1    : coalesced bf16 gather (idx/q staged in LDS, 4 lanes/row) -> per-channel
//              sum/sumsq -> shuffle+LDS reduce -> atomicAdd part1b[xcd][128]
//  K4 stage2 : inline BN1 finalize; coalesced bf16 row-gather -> h -> swizzled LDS
//              tile -> MFMA conv2; per-(n,o) max/min over k -> PACKED bf16 pair (2 MB);
//              BN2 partials -> part2b[xcd][128]
//  K5 out    : inline BN2 finalize; unpack (a2>=0 ? max : min); 64x64 LDS transpose.

#define R2 0.01f
#define INVM (1.0f / 524288.0f)

typedef __bf16 bf16x8 __attribute__((ext_vector_type(8)));
typedef float f32x4 __attribute__((ext_vector_type(4)));

__device__ __forceinline__ uint32_t pack_bf16(float a, float b) {
  uint32_t ua = __float_as_uint(a), ub = __float_as_uint(b);
  ua += 0x7fffu + ((ua >> 16) & 1u);
  ub += 0x7fffu + ((ub >> 16) & 1u);
  return (ua >> 16) | (ub & 0xffff0000u);
}
__device__ __forceinline__ float bf_lo(uint32_t v) { return __uint_as_float(v << 16); }
__device__ __forceinline__ float bf_hi(uint32_t v) { return __uint_as_float(v & 0xffff0000u); }

__device__ __forceinline__ int cell_of(float v) {
  const int c = (int)(v * 10.f);
  return c > 9 ? 9 : c;
}

// ---------------- K1: uq + prep + grid build ----------------
__global__ __launch_bounds__(1024) void k_front(const float* __restrict__ p,
                                                const float* __restrict__ x,
                                                const float* __restrict__ W1,
                                                const float* __restrict__ W2,
                                                void* __restrict__ u,
                                                float* __restrict__ q,
                                                uint32_t* __restrict__ w2frag,
                                                float* __restrict__ part1b,
                                                float* __restrict__ part2b,
                                                float4* __restrict__ cellpts,
                                                int* __restrict__ cellStart) {
  __shared__ __align__(16) char smraw[61440];
  const int bid = blockIdx.x, tid = threadIdx.x;

  if (bid < 128) {
    // ---- uq: 128 points/block, 8 threads/point ----
    float* W1s = (float*)smraw;   // transposed [c][64]
    for (int tt = tid; tt < 2240; tt += 1024) {
      const int o = tt / 35, cc = tt - o * 35;
      W1s[(cc << 6) + o] = W1[tt];
    }
    __syncthreads();
    const int t = tid & 255, sb = tid >> 8;
    const int g = (bid << 7) + (sb << 5) + (t & 31);   // global point id
    const int b = g >> 12, nl = g & 4095;
    const int os = (t >> 5) << 3;
    float f[35];
    const float* pb = p + g * 3;
    f[0] = pb[0]; f[1] = pb[1]; f[2] = pb[2];
    const float* xb = x + (b << 17) + nl;
#pragma unroll
    for (int cc = 0; cc < 32; ++cc) f[3 + cc] = xb[cc << 12];
    float acc[8];
#pragma unroll
    for (int o = 0; o < 8; ++o) acc[o] = 0.f;
#pragma unroll
    for (int cc = 0; cc < 35; ++cc) {
      const float fc = f[cc];
      const float4* wp = (const float4*)(W1s + (cc << 6) + os);
      const float4 w0 = wp[0], w1 = wp[1];
      acc[0] = fmaf(w0.x, fc, acc[0]); acc[1] = fmaf(w0.y, fc, acc[1]);
      acc[2] = fmaf(w0.z, fc, acc[2]); acc[3] = fmaf(w0.w, fc, acc[3]);
      acc[4] = fmaf(w1.x, fc, acc[4]); acc[5] = fmaf(w1.y, fc, acc[5]);
      acc[6] = fmaf(w1.z, fc, acc[6]); acc[7] = fmaf(w1.w, fc, acc[7]);
      if (cc == 2) {
        *(float4*)(q + (g << 6) + os)     = make_float4(acc[0], acc[1], acc[2], acc[3]);
        *(float4*)(q + (g << 6) + os + 4) = make_float4(acc[4], acc[5], acc[6], acc[7]);
      }
    }
    uint4 pk;
    pk.x = pack_bf16(acc[0], acc[1]);
    pk.y = pack_bf16(acc[2], acc[3]);
    pk.z = pack_bf16(acc[4], acc[5]);
    pk.w = pack_bf16(acc[6], acc[7]);
    *(uint4*)((char*)u + ((size_t)g << 7) + (os << 1)) = pk;
    return;
  }

  if (bid == 128) {
    // ---- prep: w2frag pack + zero atomic accumulators ----
    for (int tt = tid; tt < 2048; tt += 1024) {
      const int e2 = tt & 3, lane = (tt >> 2) & 63, frag = tt >> 8;
      const int kt = frag >> 2, ot = frag & 3;
      const int c0 = kt * 32 + ((lane >> 4) << 3) + e2 * 2;
      const int o = ot * 16 + (lane & 15);
      w2frag[tt] = pack_bf16(W2[(o << 6) + c0], W2[(o << 6) + c0 + 1]);
    }
    part1b[tid] = 0.f;
    part2b[tid] = 0.f;
    return;
  }

  // ---- grid build for batch (bid-129) ----
  float* px = (float*)smraw;
  float* py = px + 4096;
  float* pz = py + 4096;
  int* cnt_s = (int*)(smraw + 49152);
  int* scanA = (int*)(smraw + 53248);
  int* scanB = (int*)(smraw + 57344);
  const int b = bid - 129;
  const float* pb = p + b * 12288;
  cnt_s[tid] = 0;
  for (int i = tid; i < 4096; i += 1024) {
    px[i] = pb[3 * i]; py[i] = pb[3 * i + 1]; pz[i] = pb[3 * i + 2];
  }
  __syncthreads();
  for (int i = tid; i < 4096; i += 1024) {
    const int c = (cell_of(px[i]) * 10 + cell_of(py[i])) * 10 + cell_of(pz[i]);
    atomicAdd(&cnt_s[c], 1);
  }
  __syncthreads();
  int* src = scanA; int* dst = scanB;
  src[tid] = cnt_s[tid];
  __syncthreads();
  for (int d = 1; d < 1024; d <<= 1) {
    int v = src[tid];
    if (tid >= d) v += src[tid - d];
    dst[tid] = v;
    __syncthreads();
    int* tmp = src; src = dst; dst = tmp;
  }
  const int excl = (tid == 0) ? 0 : src[tid - 1];
  if (tid <= 1000) cellStart[b * 1001 + tid] = (tid < 1000) ? excl : src[999];
  cnt_s[tid] = excl;
  __syncthreads();
  for (int i = tid; i < 4096; i += 1024) {
    const float xx = px[i], yy = py[i], zz = pz[i];
    const int c = (cell_of(xx) * 10 + cell_of(yy)) * 10 + cell_of(zz);
    const int pos = atomicAdd(&cnt_s[c], 1);
    cellpts[(b << 12) + pos] = make_float4(xx, yy, zz, __int_as_float(i));
  }
}

// ---------------- K2: grid ball query (4 independent waves, no barriers) ----------------
__global__ __launch_bounds__(256) void k_query(const float* __restrict__ p,
                                               const float4* __restrict__ cellpts,
                                               const int* __restrict__ cellStart,
                                               int* __restrict__ idx) {
  __shared__ uint32_t bm[4][128];     // per-wave 4096-bit bitmap
  const int tid = threadIdx.x, w = tid >> 6, lane = tid & 63;
  const int blk0 = blockIdx.x;                        // 4096 blocks
  const int blkS = ((blk0 & 7) << 9) + (blk0 >> 3);   // bijective XCD swizzle
  const int n = (blkS << 2) + w;                      // query id
  const int b = n >> 12;
  bm[w][lane] = 0; bm[w][64 + lane] = 0;
  const float qx = p[n * 3], qy = p[n * 3 + 1], qz = p[n * 3 + 2];  // wave-uniform
  const int cxq = cell_of(qx), cyq = cell_of(qy), czq = cell_of(qz);

  // 9 column segments in lanes 0..8 (z-cells [cz-1,cz+1] contiguous per column)
  int cnt_l = 0, startG = 0;
  if (lane < 9) {
    const int cx = cxq + lane / 3 - 1;
    const int cy = cyq + lane % 3 - 1;
    if ((unsigned)cx < 10u && (unsigned)cy < 10u) {
      const int zlo = czq > 0 ? czq - 1 : 0;
      const int zhi = czq < 9 ? czq + 1 : 9;
      const int* cs = cellStart + b * 1001 + (cx * 10 + cy) * 10;
      startG = cs[zlo];
      cnt_l = cs[zhi + 1] - startG;
    }
  }
  int incl = cnt_l;
#pragma unroll
  for (int d = 1; d < 64; d <<= 1) { const int t = __shfl_up(incl, d); if (lane >= d) incl += t; }
  const int T = __shfl(incl, 63);
  const int base_l = startG - (incl - cnt_l);

  for (int tb = 0; tb < T; tb += 64) {
    const int t = tb + lane;
    int s = 0;
#pragma unroll
    for (int m = 0; m < 9; ++m) s += (__shfl(incl, m) <= t);
    const int a = __shfl(base_l, s < 9 ? s : 8);
    if (t < T) {
      const float4 cp = cellpts[(b << 12) + a + t];
      const float dx = cp.x - qx, dy = cp.y - qy, dz = cp.z - qz;
      // match numpy fp32 (no fma contraction, same summation order)
      const float d2 = __fadd_rn(__fadd_rn(__fmul_rn(dx, dx), __fmul_rn(dy, dy)),
                                 __fmul_rn(dz, dz));
      if (d2 < R2) {
        const int j = __float_as_int(cp.w);
        atomicOr(&bm[w][j >> 5], 1u << (j & 31));
      }
    }
  }
  __threadfence_block();

  // ascending-j extraction == "first 32 ascending, pad with first"
  const uint2 wp2 = *(const uint2*)&bm[w][2 * lane];
  unsigned long long wd = ((unsigned long long)wp2.y << 32) | wp2.x;
  const int pc = __popcll(wd);
  int ip = pc;
#pragma unroll
  for (int d = 1; d < 64; d <<= 1) { const int t = __shfl_up(ip, d); if (lane >= d) ip += t; }
  const int cntT = __shfl(ip, 63);
  int bpos = ip - pc;
  const unsigned long long nz = __ballot(wd != 0ull);
  const int fl = (int)__builtin_ctzll(nz);
  const int fv = wd ? ((lane << 6) + (int)__builtin_ctzll(wd)) : 0;
  const int first = __shfl(fv, fl);
  int* row = idx + (n << 5);
  unsigned long long ww = wd;
  while (ww && bpos < 32) {
    const int j = (lane << 6) + (int)__builtin_ctzll(ww);
    row[bpos] = j;
    ++bpos;
    ww &= ww - 1;
  }
  for (int s = cntT + lane; s < 32; s += 64) row[s] = first;
}

// ---------------- K3: BN1 stats, coalesced bf16 gather (4 lanes/row) ----------------
__global__ __launch_bounds__(256) void k_bn1(const void* __restrict__ u,
                                             const float* __restrict__ q,
                                             const int* __restrict__ idx,
                                             float* __restrict__ part1b) {
  __shared__ int idxs[512];
  __shared__ __align__(16) float qs[1024];   // 16 pts x 64 ch (f32)
  __shared__ float red[8][64];
  const int tid = threadIdx.x;
  const int blk0 = blockIdx.x;
  const int blkS = ((blk0 & 7) << 7) + (blk0 >> 3);   // bijective XCD swizzle
  const int p0 = blkS << 4;
  const int bb = (p0 >> 12) << 12;
  idxs[tid] = idx[(p0 << 5) + tid];
  idxs[256 + tid] = idx[(p0 << 5) + 256 + tid];
#pragma unroll
  for (int i = 0; i < 4; ++i) qs[(i << 8) + tid] = q[(p0 << 6) + (i << 8) + tid];
  __syncthreads();
  const int c4 = tid & 3;
  const char* ub = (const char*)u;
  float s1[16], s2[16];
#pragma unroll
  for (int i = 0; i < 16; ++i) { s1[i] = 0.f; s2[i] = 0.f; }
#pragma unroll 2
  for (int pass = 0; pass < 8; ++pass) {
    const int r = (pass << 6) + (tid >> 2);   // sample row 0..511
    const int j = idxs[r];
    const int pt = r >> 5;
    const uint4* up = (const uint4*)(ub + ((size_t)(bb + j) << 7) + (c4 << 5));
    const uint4 u0 = up[0], u1 = up[1];
    const float* qp = qs + (pt << 6) + (c4 << 4);
    const uint32_t uw[8] = {u0.x, u0.y, u0.z, u0.w, u1.x, u1.y, u1.z, u1.w};
#pragma unroll
    for (int e = 0; e < 8; ++e) {
      const float y0 = bf_lo(uw[e]) - qp[2 * e];
      const float y1 = bf_hi(uw[e]) - qp[2 * e + 1];
      s1[2 * e] += y0;     s2[2 * e] = fmaf(y0, y0, s2[2 * e]);
      s1[2 * e + 1] += y1; s2[2 * e + 1] = fmaf(y1, y1, s2[2 * e + 1]);
    }
  }
#pragma unroll
  for (int i = 0; i < 16; ++i) {
#pragma unroll
    for (int d = 4; d <= 32; d <<= 1) {
      s1[i] += __shfl_xor(s1[i], d);
      s2[i] += __shfl_xor(s2[i], d);
    }
  }
  const int w = tid >> 6, l = tid & 63;
  if (l < 4) {
#pragma unroll
    for (int i = 0; i < 16; ++i) {
      const int ch = (l << 4) + i;
      red[(w << 1)][ch] = s1[i];
      red[(w << 1) + 1][ch] = s2[i];
    }
  }
  __syncthreads();
  if (tid < 128) {
    const int ch = tid & 63, stat = tid >> 6;
    const float v = red[stat][ch] + red[2 + stat][ch] + red[4 + stat][ch] + red[6 + stat][ch];
    atomicAdd(&part1b[((blk0 & 7) << 7) + (stat << 6) + ch], v);   // XCD-private
  }
}

// ---------------- K4: coalesced bf16-gather MFMA conv2 + k-reduce + BN2 partials ----------------
__global__ __launch_bounds__(256) void k_stage2(const void* __restrict__ u,
                                                const int* __restrict__ idx,
                                                const float* __restrict__ q,
                                                const float* __restrict__ part1b,
                                                const float* __restrict__ g1,
                                                const float* __restrict__ b1,
                                                const uint32_t* __restrict__ w2frag,
                                                float* __restrict__ part2b,
                                                uint32_t* __restrict__ ymm) {
  __shared__ uint32_t hl[8192];   // 32 KB h tile: 256 samples x 128 B
  __shared__ float rs[8][64];     // rs = c1 - a1*q per (point, ch)
  __shared__ int   idxs[256];
  __shared__ float ac[128];
  __shared__ float red[8][64];
  const int tid = threadIdx.x, w = tid >> 6, l = tid & 63;
  const int blk0 = blockIdx.x;
  const int blk = ((blk0 & 7) << 8) + (blk0 >> 3);   // bijective XCD swizzle
  const int p0 = blk << 3;
  const int bb = (p0 >> 12) << 12;

  idxs[tid] = idx[(p0 << 5) + tid];
  const float qa = q[(p0 << 6) + tid];
  const float qb = q[(p0 << 6) + 256 + tid];
  if (tid < 64) {
    float s1 = 0.f, s2 = 0.f;
#pragma unroll
    for (int xx = 0; xx < 8; ++xx) {
      s1 += part1b[(xx << 7) + tid];
      s2 += part1b[(xx << 7) + 64 + tid];
    }
    const float mean = s1 * INVM, var = s2 * INVM - mean * mean;
    const float a = g1[tid] * rsqrtf(var + 1e-5f);
    ac[tid] = a; ac[64 + tid] = b1[tid] - mean * a;
  }
  __syncthreads();
  rs[tid >> 6][tid & 63] = fmaf(-ac[tid & 63], qa, ac[64 + (tid & 63)]);
  rs[4 + (tid >> 6)][tid & 63] = fmaf(-ac[tid & 63], qb, ac[64 + (tid & 63)]);
  __syncthreads();

  // ---- phase 1: bf16 row gather (4 lanes/row), h = relu(a1*u + rs), swizzled LDS
  const int c = tid & 3;
  const char* ub = (const char*)u;
  f32x4 av[4];
#pragma unroll
  for (int k = 0; k < 4; ++k) av[k] = *(const f32x4*)&ac[(c << 4) + (k << 2)];
#pragma unroll
  for (int pass = 0; pass < 4; ++pass) {
    const int r = (pass << 6) + (tid >> 2);
    const int pt = r >> 5;
    const int j = idxs[r];
    const uint4* up = (const uint4*)(ub + ((size_t)(bb + j) << 7) + (c << 5));
    const uint4 u0 = up[0], u1 = up[1];
    f32x4 rv4[4];
#pragma unroll
    for (int k = 0; k < 4; ++k) rv4[k] = *(const f32x4*)&rs[pt][(c << 4) + (k << 2)];
    const uint32_t uw8[8] = {u0.x, u0.y, u0.z, u0.w, u1.x, u1.y, u1.z, u1.w};
    uint32_t pk[8];
#pragma unroll
    for (int e = 0; e < 8; ++e) {
      const int i0 = 2 * e, i1 = 2 * e + 1;
      const float h0 = fmaxf(fmaf(av[i0 >> 2][i0 & 3], bf_lo(uw8[e]), rv4[i0 >> 2][i0 & 3]), 0.f);
      const float h1 = fmaxf(fmaf(av[i1 >> 2][i1 & 3], bf_hi(uw8[e]), rv4[i1 >> 2][i1 & 3]), 0.f);
      pk[e] = pack_bf16(h0, h1);
    }
    const int byte0 = (r << 7) + (c << 5);
    const int sw = (r & 7) << 4;
    *(uint4*)((char*)hl + (byte0 ^ sw)) = make_uint4(pk[0], pk[1], pk[2], pk[3]);
    *(uint4*)((char*)hl + ((byte0 + 16) ^ sw)) = make_uint4(pk[4], pk[5], pk[6], pk[7]);
  }

  bf16x8 bfr[8];
#pragma unroll
  for (int f = 0; f < 8; ++f)
    bfr[f] = __builtin_bit_cast(bf16x8, *(const uint4*)&w2frag[(f << 8) + (l << 2)]);
  __syncthreads();

  // ---- phase 2: per point: 16 MFMAs, stats
  float sm_[4] = {0.f, 0.f, 0.f, 0.f}, sq[4] = {0.f, 0.f, 0.f, 0.f};
#pragma unroll 1
  for (int pi = 0; pi < 2; ++pi) {
    const int ptl = (w << 1) + pi;
    const int pn = p0 + ptl;
    float mx[4], mn[4];
#pragma unroll
    for (int ot = 0; ot < 4; ++ot) { mx[ot] = -3e38f; mn[ot] = 3e38f; }
#pragma unroll
    for (int kt2 = 0; kt2 < 2; ++kt2) {
      bf16x8 afr[2];
#pragma unroll
      for (int kt = 0; kt < 2; ++kt) {
        const int srow = (ptl << 5) + (kt2 << 4) + (l & 15);
        int byte = (srow << 7) + (kt << 6) + ((l >> 4) << 4);
        byte ^= (srow & 7) << 4;
        afr[kt] = *(const bf16x8*)((const char*)hl + byte);
      }
#pragma unroll
      for (int ot = 0; ot < 4; ++ot) {
        f32x4 acc = {0.f, 0.f, 0.f, 0.f};
        acc = __builtin_amdgcn_mfma_f32_16x16x32_bf16(afr[0], bfr[ot], acc, 0, 0, 0);
        acc = __builtin_amdgcn_mfma_f32_16x16x32_bf16(afr[1], bfr[4 + ot], acc, 0, 0, 0);
#pragma unroll
        for (int e = 0; e < 4; ++e) {
          const float v = acc[e];
          mx[ot] = fmaxf(mx[ot], v); mn[ot] = fminf(mn[ot], v);
          sm_[ot] += v; sq[ot] = fmaf(v, v, sq[ot]);
        }
      }
    }
#pragma unroll
    for (int ot = 0; ot < 4; ++ot) {
      float a = fmaxf(mx[ot], __shfl_xor(mx[ot], 16)); a = fmaxf(a, __shfl_xor(a, 32));
      float b = fminf(mn[ot], __shfl_xor(mn[ot], 16)); b = fminf(b, __shfl_xor(b, 32));
      const int o = (ot << 4) + (l & 15);
      if (l < 16) ymm[(pn << 6) + o] = pack_bf16(a, b);   // (max, min) packed
    }
  }
#pragma unroll
  for (int ot = 0; ot < 4; ++ot) {
    float s = sm_[ot]; s += __shfl_xor(s, 16); s += __shfl_xor(s, 32);
    float t2 = sq[ot]; t2 += __shfl_xor(t2, 16); t2 += __shfl_xor(t2, 32);
    if (l < 16) { red[w][(ot << 4) + l] = s; red[4 + w][(ot << 4) + l] = t2; }
  }
  __syncthreads();
  if (tid < 128) {
    const int ch = tid & 63, sel = (tid >= 64) ? 4 : 0;
    const float v = red[sel][ch] + red[sel + 1][ch] + red[sel + 2][ch] + red[sel + 3][ch];
    atomicAdd(&part2b[((blk0 & 7) << 7) + tid], v);
  }
}

// ---------------- K5: output (inline a2c2 + unpack + LDS 64x64 transpose) ----------------
__global__ __launch_bounds__(256) void k_out(const uint32_t* __restrict__ ymm,
                                             const float* __restrict__ part2b,
                                             const float* __restrict__ g2,
                                             const float* __restrict__ b2,
                                             float* __restrict__ out) {
  __shared__ float ac[128];
  __shared__ float tile[64][65];
  const int tid = threadIdx.x;
  if (tid < 64) {
    float s1 = 0.f, s2 = 0.f;
#pragma unroll
    for (int xx = 0; xx < 8; ++xx) {
      s1 += part2b[(xx << 7) + tid];
      s2 += part2b[(xx << 7) + 64 + tid];
    }
    const float mean = s1 * INVM, var = s2 * INVM - mean * mean;
    const float a = g2[tid] * rsqrtf(var + 1e-5f);
    ac[tid] = a; ac[64 + tid] = b2[tid] - mean * a;
  }
  __syncthreads();
  const int b = blockIdx.x >> 6, nt = blockIdx.x & 63;
  const int pnbase = (b << 12) + (nt << 6);
#pragma unroll
  for (int i = 0; i < 16; ++i) {
    const int e = i * 256 + tid;
    const int nl = e >> 6, o = e & 63;
    const float a = ac[o], c = ac[64 + o];
    const uint32_t v = ymm[((pnbase + nl) << 6) + o];
    const float val = (a >= 0.f) ? bf_lo(v) : bf_hi(v);
    tile[nl][o] = fmaxf(fmaf(a, val, c), 0.f);
  }
  __syncthreads();
#pragma unroll
  for (int i = 0; i < 16; ++i) {
    const int e = i * 256 + tid;
    const int ol = e >> 6, nl = e & 63;
    out[(b << 18) + (ol << 12) + (nt << 6) + nl] = tile[nl][ol];
  }
}

extern "C" void kernel_launch(void* const* d_in, const int* in_sizes, int n_in,
                              void* d_out, int out_size, void* d_ws, size_t ws_size,
                              hipStream_t stream) {
  const float* p  = (const float*)d_in[0];
  const float* x  = (const float*)d_in[1];
  const float* W1 = (const float*)d_in[2];
  const float* g1 = (const float*)d_in[3];
  const float* b1 = (const float*)d_in[4];
  const float* W2 = (const float*)d_in[5];
  const float* g2 = (const float*)d_in[6];
  const float* b2 = (const float*)d_in[7];
  float* out = (float*)d_out;

  char* ws = (char*)d_ws;
  size_t off = 0;
  int* idx        = (int*)(ws + off);      off += 2097152;   // B*N*32 int
  void* u         = (void*)(ws + off);     off += 2097152;   // B*N*64 bf16
  float* q        = (float*)(ws + off);    off += 4194304;   // B*N*64 f32
  uint32_t* w2f   = (uint32_t*)(ws + off); off += 8192;
  float* part1b   = (float*)(ws + off);    off += 4096;      // [8][128] XCD-private
  float* part2b   = (float*)(ws + off);    off += 4096;
  uint32_t* ymm   = (uint32_t*)(ws + off); off += 2097152;   // [pn][o] packed (max,min)
  float4* cellpts = (float4*)(ws + off);   off += 262144;    // [B][4096] float4
  int* cellStart  = (int*)(ws + off);      off += 16384;     // [B][1001]

  k_front<<<dim3(133), dim3(1024), 0, stream>>>(p, x, W1, W2, u, q, w2f,
                                                part1b, part2b, cellpts, cellStart);
  k_query<<<dim3(4096), dim3(256), 0, stream>>>(p, cellpts, cellStart, idx);
  k_bn1<<<dim3(1024), dim3(256), 0, stream>>>(u, q, idx, part1b);
  k_stage2<<<dim3(2048), dim3(256), 0, stream>>>(u, idx, q, part1b, g1, b1, w2f,
                                                 part2b, ymm);
  k_out<<<dim3(256), dim3(256), 0, stream>>>(ymm, part2b, g2, b2, out);
}